// Round 12
// baseline (21.571 us; speedup 1.0000x reference)
//
#include <hip/hip_runtime.h>
#include <math.h>

#define EPSN 1e-12f

typedef __attribute__((ext_vector_type(8))) __bf16 bf16x8;
typedef __attribute__((ext_vector_type(8))) short short8;
typedef __attribute__((ext_vector_type(4))) float floatx4;

static __device__ __forceinline__ unsigned short f2bf(float f) {
    return __builtin_bit_cast(unsigned short, (__bf16)f);
}

// ---------------------------------------------------------------------------
// Single-dispatch fused kernel. grid 256 (1 block/CU), 512 threads (8 waves).
// Block = bc-group of 8, all 4 e, all 128 m.
//   ssq:     rnorm_reg[4] per-lane (4-lane shfl_xor reduce), no LDS.
//   phase-1: x -> 32 regs (read ONCE), VALU x@W -> xw LDS [4e][32r][128n] swz.
//   at:      A[e] transpose -> 32KB LDS, T14 async-split (issue loads for e+1
//            before compute-e, LDS-write after the sync). Single buffer.
//   phase-2 per e: wave w owns m=w*16+cl; af[2][4] from xw, bfr[4] from at,
//            8 MFMA; epilogue rnorm*relu, coalesced float4 stores.
// LDS = 32KB xw + 32KB at = 64KB exactly. No workspace, no 2nd kernel.
// ---------------------------------------------------------------------------
__global__ __launch_bounds__(512, 2)
void gcn_one(const float* __restrict__ x, const float* __restrict__ A,
             const float* __restrict__ W, float* __restrict__ out) {
    __shared__ __align__(16) unsigned char xw[32768];  // [4e][32r][128n] bf16, swz
    __shared__ __align__(16) unsigned char at[32768];  // [128m][16 n-octets], swz

    const int t   = threadIdx.x;
    const int bc0 = blockIdx.x * 8;
    const int w   = t >> 6;            // wave 0..7
    const int l   = t & 63;
    const int cl  = l & 15;
    const int lg  = l >> 4;
    const int mw  = w * 16 + cl;       // this lane's m (ssq + phase-2)
    const int mt  = t & 127;           // transpose: m-lane
    const int og  = t >> 7;            // transpose: octet-group (wave-uniform)

    // ---- issue A[0] stage loads (fly under ssq + phase-1) ----
    float v[4][8];
    #pragma unroll
    for (int q = 0; q < 4; ++q) {
        int n0 = (og * 4 + q) * 8;
        #pragma unroll
        for (int j = 0; j < 8; ++j)
            v[q][j] = A[(n0 + j) * 128 + mt];          // coalesced in mt
    }

    // ---- ssq -> rnorm_reg[4]: lg-split n-range + shfl_xor reduce ----
    float rnorm_reg[4];
    #pragma unroll 1
    for (int e = 0; e < 4; ++e) {
        const float* Ae = A + e * 16384 + mw;
        float s = 0.f;
        #pragma unroll 8
        for (int j = 0; j < 32; ++j) {
            float a = Ae[(size_t)(lg * 32 + j) * 128];
            s += a * a;
        }
        s += __shfl_xor(s, 16);
        s += __shfl_xor(s, 32);
        rnorm_reg[e] = 1.0f / fmaxf(sqrtf(s), EPSN);
    }

    // ---- phase-1: x -> regs (once), x@W -> xw LDS (R7-verified layout) ----
    float4 xf[2][4];
    #pragma unroll
    for (int p = 0; p < 2; ++p) {
        int pair = p * 512 + t;                        // 0..1023 = 8bc x 128n
        int bcl = pair >> 7, n = pair & 127;
        const float4* xp = (const float4*)(x + ((size_t)(bc0 + bcl) * 128 + n) * 16);
        xf[p][0] = xp[0]; xf[p][1] = xp[1]; xf[p][2] = xp[2]; xf[p][3] = xp[3];
    }
    #pragma unroll 1
    for (int e = 0; e < 4; ++e) {
        const float* We = W + e * 64;                  // uniform -> scalar loads
        #pragma unroll
        for (int p = 0; p < 2; ++p) {
            int pair = p * 512 + t;
            int bcl = pair >> 7, n = pair & 127;
            float a0 = 0.f, a1 = 0.f, a2 = 0.f, a3 = 0.f;
            #pragma unroll
            for (int f = 0; f < 16; ++f) {
                float xv = ((const float*)&xf[p][f >> 2])[f & 3];
                a0 += xv * We[f * 4 + 0];
                a1 += xv * We[f * 4 + 1];
                a2 += xv * We[f * 4 + 2];
                a3 += xv * We[f * 4 + 3];
            }
            float av[4] = {a0, a1, a2, a3};
            #pragma unroll
            for (int o = 0; o < 4; ++o) {
                int r = bcl * 4 + o;
                int off = (((e * 32 + r) << 8) + n * 2) ^ ((r & 7) << 4);
                *(unsigned short*)(xw + off) = f2bf(av[o]);
            }
        }
    }

    // ---- write at[0] from staged regs ----
    #pragma unroll
    for (int q = 0; q < 4; ++q) {
        int oct = og * 4 + q;
        unsigned short hs[8] __attribute__((aligned(16)));
        #pragma unroll
        for (int j = 0; j < 8; ++j) hs[j] = f2bf(v[q][j]);
        *(short8*)(at + ((mt << 8) | ((oct ^ (mt & 7)) << 4))) = *(const short8*)hs;
    }
    __syncthreads();

    // ---- per-e: compute + T14 async-staged next-e transpose ----
    #pragma unroll 1
    for (int e = 0; e < 4; ++e) {
        if (e < 3) {                                   // issue next-e loads now
            const float* An = A + (e + 1) * 16384;
            #pragma unroll
            for (int q = 0; q < 4; ++q) {
                int n0 = (og * 4 + q) * 8;
                #pragma unroll
                for (int j = 0; j < 8; ++j)
                    v[q][j] = An[(n0 + j) * 128 + mt];
            }
        }
        // af from xw (R7-verified), bfr from at (R11-verified)
        bf16x8 af[2][4];
        #pragma unroll
        for (int rt = 0; rt < 2; ++rt)
            #pragma unroll
            for (int ks = 0; ks < 4; ++ks) {
                int row = rt * 16 + cl;
                int off = (((e * 32 + row) << 8) + (ks * 32 + lg * 8) * 2)
                          ^ ((row & 7) << 4);
                af[rt][ks] = __builtin_bit_cast(bf16x8, *(const short8*)(xw + off));
            }
        bf16x8 bfr[4];
        #pragma unroll
        for (int ks = 0; ks < 4; ++ks) {
            int slot = (ks * 4 + lg) ^ (mw & 7);
            bfr[ks] = __builtin_bit_cast(bf16x8,
                *(const short8*)(at + ((mw << 8) | (slot << 4))));
        }

        floatx4 acc0 = {0.f, 0.f, 0.f, 0.f};
        floatx4 acc1 = {0.f, 0.f, 0.f, 0.f};
        #pragma unroll
        for (int ks = 0; ks < 4; ++ks) {
            acc0 = __builtin_amdgcn_mfma_f32_16x16x32_bf16(af[0][ks], bfr[ks], acc0, 0, 0, 0);
            acc1 = __builtin_amdgcn_mfma_f32_16x16x32_bf16(af[1][ks], bfr[ks], acc1, 0, 0, 0);
        }

        // epilogue: D col=cl -> m=mw; row=lg*4+q -> r=rt*16+lg*4+q
        //           -> bc = bc0 + rt*4 + lg, o=q
        float rn = rnorm_reg[e];
        #pragma unroll
        for (int rt = 0; rt < 2; ++rt) {
            floatx4 a = rt ? acc1 : acc0;
            int bc = bc0 + rt * 4 + lg;
            int b = bc >> 4, c = bc & 15;
            float4 o4;
            o4.x = fmaxf(a[0] * rn, 0.f);
            o4.y = fmaxf(a[1] * rn, 0.f);
            o4.z = fmaxf(a[2] * rn, 0.f);
            o4.w = fmaxf(a[3] * rn, 0.f);
            ((float4*)out)[(size_t)(b * 64 + e * 16 + c) * 128 + mw] = o4;
        }
        __syncthreads();                               // all reads of at done
        if (e < 3) {                                   // late LDS write (T14)
            #pragma unroll
            for (int q = 0; q < 4; ++q) {
                int oct = og * 4 + q;
                unsigned short hs[8] __attribute__((aligned(16)));
                #pragma unroll
                for (int j = 0; j < 8; ++j) hs[j] = f2bf(v[q][j]);
                *(short8*)(at + ((mt << 8) | ((oct ^ (mt & 7)) << 4))) =
                    *(const short8*)hs;
            }
            __syncthreads();                           // at[e+1] ready
        }
    }
}

extern "C" void kernel_launch(void* const* d_in, const int* in_sizes, int n_in,
                              void* d_out, int out_size, void* d_ws, size_t ws_size,
                              hipStream_t stream) {
    const float* x = (const float*)d_in[0];   // [128,16,128,16]
    const float* A = (const float*)d_in[1];   // [4,128,128]
    const float* W = (const float*)d_in[2];   // [4,16,4]
    float* out = (float*)d_out;               // [128,64,128,4]

    gcn_one<<<256, 512, 0, stream>>>(x, A, W, out);
}

// Round 14
// 19.719 us; speedup vs baseline: 1.0939x; 1.0939x over previous
//
#include <hip/hip_runtime.h>
#include <math.h>

#define EPSN 1e-12f

typedef __attribute__((ext_vector_type(8))) __bf16 bf16x8;
typedef __attribute__((ext_vector_type(8))) short short8;
typedef __attribute__((ext_vector_type(4))) float floatx4;

static __device__ __forceinline__ unsigned short f2bf(float f) {
    return __builtin_bit_cast(unsigned short, (__bf16)f);
}

// ---------------------------------------------------------------------------
// Single-dispatch fused kernel. grid 256 (1 block/CU), 512 threads (8 waves).
// Block = bc-group of 8, all 4 e, all 128 m.
//   phase-1: x -> 32 regs (read ONCE), VALU x@W -> xw LDS [4e][32r][128n] swz.
//   at:      A[e] transpose -> 32KB LDS, T14 async-split; ssq FOLDED into the
//            transpose (R9-verified): red[og][mt] = per-column f32 partials,
//            epilogue reduces 4 partials -> rnorm. No separate ssq pass.
//   phase-2 per e: wave w owns m=w*16+cl; af[2][4] from xw, bfr[4] from at,
//            8 MFMA; epilogue rnorm*relu, coalesced float4 stores.
// LDS = 32KB xw + 32KB at + 2KB red. No workspace, single kernel.
// ---------------------------------------------------------------------------
__global__ __launch_bounds__(512, 2)
void gcn_one(const float* __restrict__ x, const float* __restrict__ A,
             const float* __restrict__ W, float* __restrict__ out) {
    __shared__ __align__(16) unsigned char xw[32768];  // [4e][32r][128n] bf16, swz
    __shared__ __align__(16) unsigned char at[32768];  // [128m][16 n-octets], swz
    __shared__ float red[4][128];                      // ssq partials (cur e)

    const int t   = threadIdx.x;
    const int bc0 = blockIdx.x * 8;
    const int w   = t >> 6;            // wave 0..7
    const int l   = t & 63;
    const int cl  = l & 15;
    const int lg  = l >> 4;
    const int mw  = w * 16 + cl;       // this lane's m (phase-2)
    const int mt  = t & 127;           // transpose: m-lane (column owner)
    const int og  = t >> 7;            // transpose: octet-group (wave-uniform)

    // ---- issue A[0] stage loads (fly under phase-1) ----
    float v[4][8];
    #pragma unroll
    for (int q = 0; q < 4; ++q) {
        int n0 = (og * 4 + q) * 8;
        #pragma unroll
        for (int j = 0; j < 8; ++j)
            v[q][j] = A[(n0 + j) * 128 + mt];          // coalesced in mt
    }

    // ---- phase-1: x -> regs (once), x@W -> xw LDS (R7-verified layout) ----
    float4 xf[2][4];
    #pragma unroll
    for (int p = 0; p < 2; ++p) {
        int pair = p * 512 + t;                        // 0..1023 = 8bc x 128n
        int bcl = pair >> 7, n = pair & 127;
        const float4* xp = (const float4*)(x + ((size_t)(bc0 + bcl) * 128 + n) * 16);
        xf[p][0] = xp[0]; xf[p][1] = xp[1]; xf[p][2] = xp[2]; xf[p][3] = xp[3];
    }
    #pragma unroll 1
    for (int e = 0; e < 4; ++e) {
        const float* We = W + e * 64;                  // uniform -> scalar loads
        #pragma unroll
        for (int p = 0; p < 2; ++p) {
            int pair = p * 512 + t;
            int bcl = pair >> 7, n = pair & 127;
            float a0 = 0.f, a1 = 0.f, a2 = 0.f, a3 = 0.f;
            #pragma unroll
            for (int f = 0; f < 16; ++f) {
                float xv = ((const float*)&xf[p][f >> 2])[f & 3];
                a0 += xv * We[f * 4 + 0];
                a1 += xv * We[f * 4 + 1];
                a2 += xv * We[f * 4 + 2];
                a3 += xv * We[f * 4 + 3];
            }
            float av[4] = {a0, a1, a2, a3};
            #pragma unroll
            for (int o = 0; o < 4; ++o) {
                int r = bcl * 4 + o;
                int off = (((e * 32 + r) << 8) + n * 2) ^ ((r & 7) << 4);
                *(unsigned short*)(xw + off) = f2bf(av[o]);
            }
        }
    }

    // ---- write at[0] + ssq partials from staged regs (R9-verified fold) ----
    {
        float ssq = 0.f;
        #pragma unroll
        for (int q = 0; q < 4; ++q) {
            int oct = og * 4 + q;
            unsigned short hs[8] __attribute__((aligned(16)));
            #pragma unroll
            for (int j = 0; j < 8; ++j) {
                ssq += v[q][j] * v[q][j];
                hs[j] = f2bf(v[q][j]);
            }
            *(short8*)(at + ((mt << 8) | ((oct ^ (mt & 7)) << 4))) = *(const short8*)hs;
        }
        red[og][mt] = ssq;
    }
    __syncthreads();

    // ---- per-e: compute + T14 async-staged next-e transpose ----
    #pragma unroll 1
    for (int e = 0; e < 4; ++e) {
        if (e < 3) {                                   // issue next-e loads now
            const float* An = A + (e + 1) * 16384;
            #pragma unroll
            for (int q = 0; q < 4; ++q) {
                int n0 = (og * 4 + q) * 8;
                #pragma unroll
                for (int j = 0; j < 8; ++j)
                    v[q][j] = An[(n0 + j) * 128 + mt];
            }
        }
        // af from xw (R7-verified), bfr from at (R11-verified)
        bf16x8 af[2][4];
        #pragma unroll
        for (int rt = 0; rt < 2; ++rt)
            #pragma unroll
            for (int ks = 0; ks < 4; ++ks) {
                int row = rt * 16 + cl;
                int off = (((e * 32 + row) << 8) + (ks * 32 + lg * 8) * 2)
                          ^ ((row & 7) << 4);
                af[rt][ks] = __builtin_bit_cast(bf16x8, *(const short8*)(xw + off));
            }
        bf16x8 bfr[4];
        #pragma unroll
        for (int ks = 0; ks < 4; ++ks) {
            int slot = (ks * 4 + lg) ^ (mw & 7);
            bfr[ks] = __builtin_bit_cast(bf16x8,
                *(const short8*)(at + ((mw << 8) | (slot << 4))));
        }

        floatx4 acc0 = {0.f, 0.f, 0.f, 0.f};
        floatx4 acc1 = {0.f, 0.f, 0.f, 0.f};
        #pragma unroll
        for (int ks = 0; ks < 4; ++ks) {
            acc0 = __builtin_amdgcn_mfma_f32_16x16x32_bf16(af[0][ks], bfr[ks], acc0, 0, 0, 0);
            acc1 = __builtin_amdgcn_mfma_f32_16x16x32_bf16(af[1][ks], bfr[ks], acc1, 0, 0, 0);
        }

        // rnorm for (e, mw): reduce the 4 column partials (read BEFORE the
        // barrier that lets the next-e transpose overwrite red)
        float s = red[0][mw] + red[1][mw] + red[2][mw] + red[3][mw];
        float rn = 1.0f / fmaxf(sqrtf(s), EPSN);

        // epilogue: D col=cl -> m=mw; row=lg*4+q -> r=rt*16+lg*4+q
        //           -> bc = bc0 + rt*4 + lg, o=q
        #pragma unroll
        for (int rt = 0; rt < 2; ++rt) {
            floatx4 a = rt ? acc1 : acc0;
            int bc = bc0 + rt * 4 + lg;
            int b = bc >> 4, c = bc & 15;
            float4 o4;
            o4.x = fmaxf(a[0] * rn, 0.f);
            o4.y = fmaxf(a[1] * rn, 0.f);
            o4.z = fmaxf(a[2] * rn, 0.f);
            o4.w = fmaxf(a[3] * rn, 0.f);
            ((float4*)out)[(size_t)(b * 64 + e * 16 + c) * 128 + mw] = o4;
        }
        __syncthreads();                               // all reads of at/red done
        if (e < 3) {                                   // late LDS write (T14)
            float ssq = 0.f;
            #pragma unroll
            for (int q = 0; q < 4; ++q) {
                int oct = og * 4 + q;
                unsigned short hs[8] __attribute__((aligned(16)));
                #pragma unroll
                for (int j = 0; j < 8; ++j) {
                    ssq += v[q][j] * v[q][j];
                    hs[j] = f2bf(v[q][j]);
                }
                *(short8*)(at + ((mt << 8) | ((oct ^ (mt & 7)) << 4))) =
                    *(const short8*)hs;
            }
            red[og][mt] = ssq;
            __syncthreads();                           // at/red[e+1] ready
        }
    }
}

extern "C" void kernel_launch(void* const* d_in, const int* in_sizes, int n_in,
                              void* d_out, int out_size, void* d_ws, size_t ws_size,
                              hipStream_t stream) {
    const float* x = (const float*)d_in[0];   // [128,16,128,16]
    const float* A = (const float*)d_in[1];   // [4,128,128]
    const float* W = (const float*)d_in[2];   // [4,16,4]
    float* out = (float*)d_out;               // [128,64,128,4]

    gcn_one<<<256, 512, 0, stream>>>(x, A, W, out);
}

// Round 15
// 18.959 us; speedup vs baseline: 1.1378x; 1.0401x over previous
//
#include <hip/hip_runtime.h>
#include <math.h>

#define EPSN 1e-12f

typedef __attribute__((ext_vector_type(8))) __bf16 bf16x8;
typedef __attribute__((ext_vector_type(8))) short short8;
typedef __attribute__((ext_vector_type(4))) float floatx4;

static __device__ __forceinline__ unsigned short f2bf(float f) {
    return __builtin_bit_cast(unsigned short, (__bf16)f);
}

// ---------------------------------------------------------------------------
// Single-dispatch fused kernel. grid 256 (1 block/CU), 512 threads (8 waves).
// Block = bc-group of 8, all 4 e, all 128 m.
//   phase-1 (MFMA): XW (M=1024 x-rows, N=16=(e,o), K=16 zero-padded to 32)
//     via mfma_f32_16x16x32_bf16, 8 MFMA/wave; D scatter -> xw LDS
//     [4e][32r][128n] with the R7-verified ((r&7)<<4) XOR swizzle.
//   A-stage (dwordx4): thread owns m-quad (m=mq*4+i) x n-octet (n=ng*8+j);
//     8 dwordx4 loads/estep (was 32 scalar); at slot = oct ^ ((m>>2)&7)
//     (bijective, same formula on write+read); ssq -> red[16][128] f32.
//   phase-2 per e (R14 verbatim except bfr slot formula): wave w owns
//     m=w*16+cl; af[2][4] from xw, bfr[4] from at, 8 MFMA; epilogue
//     rnorm*relu, coalesced float4 stores. T14 async next-e staging.
// LDS = 32KB xw + 32KB at + 8KB red = 72KB -> 2 blocks/CU budget.
// ---------------------------------------------------------------------------
__global__ __launch_bounds__(512, 2)
void gcn_one(const float* __restrict__ x, const float* __restrict__ A,
             const float* __restrict__ W, float* __restrict__ out) {
    __shared__ __align__(16) unsigned char xw[32768];  // [4e][32r][128n] bf16, swz
    __shared__ __align__(16) unsigned char at[32768];  // [128m][16 n-octets], swz
    __shared__ float red[16][128];                     // ssq partials (cur e)

    const int t   = threadIdx.x;
    const int bc0 = blockIdx.x * 8;
    const int w   = t >> 6;            // wave 0..7
    const int l   = t & 63;
    const int cl  = l & 15;
    const int lg  = l >> 4;
    const int mw  = w * 16 + cl;       // this lane's m (phase-2)
    const int mq  = t & 31;            // A-stage: m-quad (m = mq*4+i)
    const int ng  = t >> 5;            // A-stage: n-octet (n = ng*8+j)

    // ---- issue A[0] stage loads: 8 dwordx4 (fly under phase-1) ----
    float4 v4[8];
    #pragma unroll
    for (int j = 0; j < 8; ++j)
        v4[j] = *(const float4*)(A + (size_t)(ng * 8 + j) * 128 + mq * 4);

    // ---- phase-1: XW via MFMA.  B-frag = W^T col (e,o)=cl, k<16 real ----
    bf16x8 bW;
    {
        short8 z = {0, 0, 0, 0, 0, 0, 0, 0};
        bW = __builtin_bit_cast(bf16x8, z);
        if (lg < 2) {
            unsigned short hs[8] __attribute__((aligned(16)));
            #pragma unroll
            for (int j = 0; j < 8; ++j)
                hs[j] = f2bf(W[(cl >> 2) * 64 + (lg * 8 + j) * 4 + (cl & 3)]);
            bW = __builtin_bit_cast(bf16x8, *(const short8*)hs);
        }
    }
    #pragma unroll
    for (int ti = 0; ti < 8; ++ti) {
        int T = w * 8 + ti;                       // row-tile 0..63
        bf16x8 ax;
        { short8 z = {0, 0, 0, 0, 0, 0, 0, 0}; ax = __builtin_bit_cast(bf16x8, z); }
        if (lg < 2) {
            int R = T * 16 + cl;                  // local x-row 0..1023
            const float* xp = x + ((size_t)bc0 * 128 + R) * 16 + lg * 8;
            float4 a = *(const float4*)xp;
            float4 b = *(const float4*)(xp + 4);
            unsigned short hs[8] __attribute__((aligned(16)));
            hs[0] = f2bf(a.x); hs[1] = f2bf(a.y); hs[2] = f2bf(a.z); hs[3] = f2bf(a.w);
            hs[4] = f2bf(b.x); hs[5] = f2bf(b.y); hs[6] = f2bf(b.z); hs[7] = f2bf(b.w);
            ax = __builtin_bit_cast(bf16x8, *(const short8*)hs);
        }
        floatx4 d = {0.f, 0.f, 0.f, 0.f};
        d = __builtin_amdgcn_mfma_f32_16x16x32_bf16(ax, bW, d, 0, 0, 0);
        // D: col=cl=(e,o); row=lg*4+q -> local row R'=T*16+lg*4+q
        int eD = cl >> 2, oD = cl & 3;
        int bcl = T >> 3;                         // R'>>7
        int nb  = (T & 7) * 16 + lg * 4;          // R'&127 base
        int r   = bcl * 4 + oD;
        int base = (eD * 32 + r) << 8;
        int s    = (r & 7) << 4;
        #pragma unroll
        for (int q = 0; q < 4; ++q) {
            int off = (base + (nb + q) * 2) ^ s;
            *(unsigned short*)(xw + off) = f2bf(d[q]);
        }
    }

    // ---- write at[0] + red from staged regs ----
    {
        floatx4 rs = {0.f, 0.f, 0.f, 0.f};
        #pragma unroll
        for (int i = 0; i < 4; ++i) {
            int m = mq * 4 + i;
            unsigned short hs[8] __attribute__((aligned(16)));
            #pragma unroll
            for (int j = 0; j < 8; ++j) {
                float vv = ((const float*)&v4[j])[i];
                rs[i] += vv * vv;
                hs[j] = f2bf(vv);
            }
            int slot = ng ^ (mq & 7);             // oct ^ ((m>>2)&7)
            *(short8*)(at + ((m << 8) | (slot << 4))) = *(const short8*)hs;
        }
        *(float4*)&red[ng][mq * 4] = *(const float4*)&rs;
    }
    __syncthreads();

    // ---- per-e: compute + T14 async-staged next-e ----
    #pragma unroll 1
    for (int e = 0; e < 4; ++e) {
        if (e < 3) {                              // issue next-e loads now
            const float* An = A + (size_t)(e + 1) * 16384;
            #pragma unroll
            for (int j = 0; j < 8; ++j)
                v4[j] = *(const float4*)(An + (size_t)(ng * 8 + j) * 128 + mq * 4);
        }
        // af from xw (R7/R14-verified)
        bf16x8 af[2][4];
        #pragma unroll
        for (int rt = 0; rt < 2; ++rt)
            #pragma unroll
            for (int ks = 0; ks < 4; ++ks) {
                int row = rt * 16 + cl;
                int off = (((e * 32 + row) << 8) + (ks * 32 + lg * 8) * 2)
                          ^ ((row & 7) << 4);
                af[rt][ks] = __builtin_bit_cast(bf16x8, *(const short8*)(xw + off));
            }
        // bfr from at (slot = oct ^ ((mw>>2)&7))
        bf16x8 bfr[4];
        #pragma unroll
        for (int ks = 0; ks < 4; ++ks) {
            int slot = (ks * 4 + lg) ^ ((mw >> 2) & 7);
            bfr[ks] = __builtin_bit_cast(bf16x8,
                *(const short8*)(at + ((mw << 8) | (slot << 4))));
        }

        floatx4 acc0 = {0.f, 0.f, 0.f, 0.f};
        floatx4 acc1 = {0.f, 0.f, 0.f, 0.f};
        #pragma unroll
        for (int ks = 0; ks < 4; ++ks) {
            acc0 = __builtin_amdgcn_mfma_f32_16x16x32_bf16(af[0][ks], bfr[ks], acc0, 0, 0, 0);
            acc1 = __builtin_amdgcn_mfma_f32_16x16x32_bf16(af[1][ks], bfr[ks], acc1, 0, 0, 0);
        }

        // rnorm: reduce 16 column partials (before overwrite barrier)
        float ssum = 0.f;
        #pragma unroll
        for (int g = 0; g < 16; ++g) ssum += red[g][mw];
        float rn = 1.0f / fmaxf(sqrtf(ssum), EPSN);

        // epilogue: D col=cl -> m=mw; row=lg*4+q -> r=rt*16+lg*4+q
        //           -> bc = bc0 + rt*4 + lg, o=q
        #pragma unroll
        for (int rt = 0; rt < 2; ++rt) {
            floatx4 a = rt ? acc1 : acc0;
            int bc = bc0 + rt * 4 + lg;
            int b = bc >> 4, c = bc & 15;
            float4 o4;
            o4.x = fmaxf(a[0] * rn, 0.f);
            o4.y = fmaxf(a[1] * rn, 0.f);
            o4.z = fmaxf(a[2] * rn, 0.f);
            o4.w = fmaxf(a[3] * rn, 0.f);
            ((float4*)out)[(size_t)(b * 64 + e * 16 + c) * 128 + mw] = o4;
        }
        __syncthreads();                          // all reads of at/red done
        if (e < 3) {                              // late LDS write (T14)
            floatx4 rs = {0.f, 0.f, 0.f, 0.f};
            #pragma unroll
            for (int i = 0; i < 4; ++i) {
                int m = mq * 4 + i;
                unsigned short hs[8] __attribute__((aligned(16)));
                #pragma unroll
                for (int j = 0; j < 8; ++j) {
                    float vv = ((const float*)&v4[j])[i];
                    rs[i] += vv * vv;
                    hs[j] = f2bf(vv);
                }
                int slot = ng ^ (mq & 7);
                *(short8*)(at + ((m << 8) | (slot << 4))) = *(const short8*)hs;
            }
            *(float4*)&red[ng][mq * 4] = *(const float4*)&rs;
            __syncthreads();                      // at/red[e+1] ready
        }
    }
}

extern "C" void kernel_launch(void* const* d_in, const int* in_sizes, int n_in,
                              void* d_out, int out_size, void* d_ws, size_t ws_size,
                              hipStream_t stream) {
    const float* x = (const float*)d_in[0];   // [128,16,128,16]
    const float* A = (const float*)d_in[1];   // [4,128,128]
    const float* W = (const float*)d_in[2];   // [4,16,4]
    float* out = (float*)d_out;               // [128,64,128,4]

    gcn_one<<<256, 512, 0, stream>>>(x, A, W, out);
}

// Round 16
// 18.530 us; speedup vs baseline: 1.1641x; 1.0231x over previous
//
#include <hip/hip_runtime.h>
#include <math.h>

#define EPSN 1e-12f

typedef __attribute__((ext_vector_type(8))) __bf16 bf16x8;
typedef __attribute__((ext_vector_type(8))) short short8;
typedef __attribute__((ext_vector_type(4))) float floatx4;

static __device__ __forceinline__ unsigned short f2bf(float f) {
    return __builtin_bit_cast(unsigned short, (__bf16)f);
}

// ---------------------------------------------------------------------------
// Single-dispatch fused kernel. grid 256 (1 block/CU), 512 threads (8 waves).
// R15 datapath + DOUBLE-BUFFERED at/red: compute(e) overlaps stage(e+2).
// Barriers: 7 -> 4.  LDS = 32KB xw + 2x32KB at + 2x8KB red = 112KB.
//   phase-1 (MFMA): XW (M=1024, N=16=(e,o), K=16 zero-padded) -> xw LDS, swz.
//   A-stage: thread owns m-quad x n-octet, 8 dwordx4/estep;
//            slot = oct ^ ((m>>2)&7); ssq partials -> red.
//   phase-2 per e: af[2][4] from xw, bfr[4] from at[e&1], 8 MFMA;
//            rnorm*relu epilogue, coalesced float4 stores.
// ---------------------------------------------------------------------------
__global__ __launch_bounds__(512, 2)
void gcn_one(const float* __restrict__ x, const float* __restrict__ A,
             const float* __restrict__ W, float* __restrict__ out) {
    __shared__ __align__(16) unsigned char xw[32768];     // [4e][32r][128n] swz
    __shared__ __align__(16) unsigned char at[2][32768];  // [128m][16oct] swz
    __shared__ float red[2][16][128];                     // ssq partials

    const int t   = threadIdx.x;
    const int bc0 = blockIdx.x * 8;
    const int w   = t >> 6;            // wave 0..7
    const int l   = t & 63;
    const int cl  = l & 15;
    const int lg  = l >> 4;
    const int mw  = w * 16 + cl;       // phase-2 m
    const int mq  = t & 31;            // A-stage m-quad (m = mq*4+i)
    const int ng  = t >> 5;            // A-stage n-octet (n = ng*8+j)

    // ---- issue A[0] + A[1] loads up-front (fly under phase-1) ----
    float4 v4a[8], v4b[8];
    #pragma unroll
    for (int j = 0; j < 8; ++j)
        v4a[j] = *(const float4*)(A + (size_t)(ng * 8 + j) * 128 + mq * 4);
    #pragma unroll
    for (int j = 0; j < 8; ++j)
        v4b[j] = *(const float4*)(A + 16384 + (size_t)(ng * 8 + j) * 128 + mq * 4);

    // ---- phase-1: XW via MFMA (R15-verified) ----
    bf16x8 bW;
    {
        short8 z = {0, 0, 0, 0, 0, 0, 0, 0};
        bW = __builtin_bit_cast(bf16x8, z);
        if (lg < 2) {
            unsigned short hs[8] __attribute__((aligned(16)));
            #pragma unroll
            for (int j = 0; j < 8; ++j)
                hs[j] = f2bf(W[(cl >> 2) * 64 + (lg * 8 + j) * 4 + (cl & 3)]);
            bW = __builtin_bit_cast(bf16x8, *(const short8*)hs);
        }
    }
    #pragma unroll
    for (int ti = 0; ti < 8; ++ti) {
        int T = w * 8 + ti;                       // row-tile 0..63
        bf16x8 ax;
        { short8 z = {0, 0, 0, 0, 0, 0, 0, 0}; ax = __builtin_bit_cast(bf16x8, z); }
        if (lg < 2) {
            int R = T * 16 + cl;                  // local x-row 0..1023
            const float* xp = x + ((size_t)bc0 * 128 + R) * 16 + lg * 8;
            float4 a = *(const float4*)xp;
            float4 b = *(const float4*)(xp + 4);
            unsigned short hs[8] __attribute__((aligned(16)));
            hs[0] = f2bf(a.x); hs[1] = f2bf(a.y); hs[2] = f2bf(a.z); hs[3] = f2bf(a.w);
            hs[4] = f2bf(b.x); hs[5] = f2bf(b.y); hs[6] = f2bf(b.z); hs[7] = f2bf(b.w);
            ax = __builtin_bit_cast(bf16x8, *(const short8*)hs);
        }
        floatx4 d = {0.f, 0.f, 0.f, 0.f};
        d = __builtin_amdgcn_mfma_f32_16x16x32_bf16(ax, bW, d, 0, 0, 0);
        int eD = cl >> 2, oD = cl & 3;
        int bcl = T >> 3;
        int nb  = (T & 7) * 16 + lg * 4;
        int r   = bcl * 4 + oD;
        int base = (eD * 32 + r) << 8;
        int s    = (r & 7) << 4;
        #pragma unroll
        for (int q = 0; q < 4; ++q) {
            int off = (base + (nb + q) * 2) ^ s;
            *(unsigned short*)(xw + off) = f2bf(d[q]);
        }
    }

    // ---- at/red writer (R15-verified formulas) ----
    auto stage_write = [&](int buf, const float4* v4) {
        floatx4 rs = {0.f, 0.f, 0.f, 0.f};
        #pragma unroll
        for (int i = 0; i < 4; ++i) {
            int m = mq * 4 + i;
            unsigned short hs[8] __attribute__((aligned(16)));
            #pragma unroll
            for (int j = 0; j < 8; ++j) {
                float vv = ((const float*)&v4[j])[i];
                rs[i] += vv * vv;
                hs[j] = f2bf(vv);
            }
            int slot = ng ^ (mq & 7);
            *(short8*)(at[buf] + ((m << 8) | (slot << 4))) = *(const short8*)hs;
        }
        *(float4*)&red[buf][ng][mq * 4] = *(const float4*)&rs;
    };

    stage_write(0, v4a);
    stage_write(1, v4b);
    __syncthreads();

    // ---- compute step for edge e from buffer buf ----
    auto compute_e = [&](int e, int buf) {
        bf16x8 af[2][4];
        #pragma unroll
        for (int rt = 0; rt < 2; ++rt)
            #pragma unroll
            for (int ks = 0; ks < 4; ++ks) {
                int row = rt * 16 + cl;
                int off = (((e * 32 + row) << 8) + (ks * 32 + lg * 8) * 2)
                          ^ ((row & 7) << 4);
                af[rt][ks] = __builtin_bit_cast(bf16x8, *(const short8*)(xw + off));
            }
        bf16x8 bfr[4];
        #pragma unroll
        for (int ks = 0; ks < 4; ++ks) {
            int slot = (ks * 4 + lg) ^ ((mw >> 2) & 7);
            bfr[ks] = __builtin_bit_cast(bf16x8,
                *(const short8*)(at[buf] + ((mw << 8) | (slot << 4))));
        }
        floatx4 acc0 = {0.f, 0.f, 0.f, 0.f};
        floatx4 acc1 = {0.f, 0.f, 0.f, 0.f};
        #pragma unroll
        for (int ks = 0; ks < 4; ++ks) {
            acc0 = __builtin_amdgcn_mfma_f32_16x16x32_bf16(af[0][ks], bfr[ks], acc0, 0, 0, 0);
            acc1 = __builtin_amdgcn_mfma_f32_16x16x32_bf16(af[1][ks], bfr[ks], acc1, 0, 0, 0);
        }
        float ssum = 0.f;
        #pragma unroll
        for (int g = 0; g < 16; ++g) ssum += red[buf][g][mw];
        float rn = 1.0f / fmaxf(sqrtf(ssum), EPSN);
        #pragma unroll
        for (int rt = 0; rt < 2; ++rt) {
            floatx4 a = rt ? acc1 : acc0;
            int bc = bc0 + rt * 4 + lg;
            int b = bc >> 4, c = bc & 15;
            float4 o4;
            o4.x = fmaxf(a[0] * rn, 0.f);
            o4.y = fmaxf(a[1] * rn, 0.f);
            o4.z = fmaxf(a[2] * rn, 0.f);
            o4.w = fmaxf(a[3] * rn, 0.f);
            ((float4*)out)[(size_t)(b * 64 + e * 16 + c) * 128 + mw] = o4;
        }
    };

    // ---- pipelined e-loop: compute(e) overlaps stage(e+2) ----
    // e=0: issue A[2]; compute from at0; bar; write at0<-A2
    #pragma unroll
    for (int j = 0; j < 8; ++j)
        v4a[j] = *(const float4*)(A + 2 * 16384 + (size_t)(ng * 8 + j) * 128 + mq * 4);
    compute_e(0, 0);
    __syncthreads();          // all reads of at0/red0 done
    stage_write(0, v4a);      // at0 <- A[2] (vmcnt waits handled by compiler)

    // e=1: issue A[3]; compute from at1; bar; write at1<-A3
    #pragma unroll
    for (int j = 0; j < 8; ++j)
        v4b[j] = *(const float4*)(A + 3 * 16384 + (size_t)(ng * 8 + j) * 128 + mq * 4);
    compute_e(1, 1);
    __syncthreads();          // reads of at1 done AND at0<-A2 writes done
    stage_write(1, v4b);      // at1 <- A[3]

    // e=2: compute from at0 (A2); bar ensures at1<-A3 done before e=3
    compute_e(2, 0);
    __syncthreads();

    // e=3: compute from at1 (A3)
    compute_e(3, 1);
}

extern "C" void kernel_launch(void* const* d_in, const int* in_sizes, int n_in,
                              void* d_out, int out_size, void* d_ws, size_t ws_size,
                              hipStream_t stream) {
    const float* x = (const float*)d_in[0];   // [128,16,128,16]
    const float* A = (const float*)d_in[1];   // [4,128,128]
    const float* W = (const float*)d_in[2];   // [4,16,4]
    float* out = (float*)d_out;               // [128,64,128,4]

    gcn_one<<<256, 512, 0, stream>>>(x, A, W, out);
}